// Round 6
// baseline (400.042 us; speedup 1.0000x reference)
//
#include <hip/hip_runtime.h>
#include <hip/hip_bf16.h>
#include <cstdint>
#include <cmath>

typedef unsigned long long u64;

// ---------------------------------------------------------------------------
// SparseLinear: out[b, dst[e]] += values[e] * x[b, src[e]]; out += bias
// Round 6: reduce kernel restructured into two phases per chunk:
//   (1) coalesced bulk-stage of packed records into LDS (independent loads),
//   (2) register-batched decode from LDS -> 8 independent xt gathers -> ds_add.
// This removes the pb->xt dependent global chain that serialized R4/R5
// (VGPR=20 showed the compiler never kept the 8-deep batch in flight).
// Packed edge record: [63:32]=val bits, [31:6]=src, [4:0]=dst&31.
// ---------------------------------------------------------------------------

#define RB        32          // rows per bucket
#define RB_SHIFT  5

// K0: detect int64 vs int32 indices; zero bucket cursors.
__global__ void SL_detect_zero_kernel(const uint32_t* __restrict__ raw, int* __restrict__ flag,
                                      int* __restrict__ cursor, int NB) {
    int gid = blockIdx.x * blockDim.x + threadIdx.x;
    if (gid == 0) {
        int is64 = 1;
        for (int i = 1; i < 64; i += 2) {
            if (raw[i] != 0u) { is64 = 0; break; }
        }
        *flag = is64;
    }
    for (int i = gid; i < NB; i += gridDim.x * blockDim.x) cursor[i] = 0;
}

// K1: transpose x (32, N) -> xt (N, 32) in bf16. LDS 32x33 tile.
__global__ void SL_prep_kernel(const float* __restrict__ x, __hip_bfloat16* __restrict__ xt,
                               int N) {
    __shared__ float tile[32][33];
    int n0 = blockIdx.x * 32;
    int tx = threadIdx.x, ty = threadIdx.y;
    int n = n0 + tx;
    if (n < N) tile[tx][ty] = x[(size_t)ty * N + n];
    __syncthreads();
    int n2 = n0 + ty;
    if (n2 < N) xt[(size_t)n2 * 32 + tx] = __float2bfloat16(tile[ty][tx]);
}

// K2: bucket scatter. Per-block LDS histogram + rank, one global atomic per
// (block,bucket) to reserve a contiguous slot range, packed 8B nt-writes.
#define SC_BLOCK 256
#define SC_EPT   32   // 8192 edges per block (rank fits 14 bits)
__global__ __launch_bounds__(SC_BLOCK)
void SL_bucket_scatter_kernel(const int* __restrict__ raw, const int* __restrict__ flag,
                              const float* __restrict__ vals, u64* __restrict__ packed,
                              int* __restrict__ cursor, long long E, int NB, int CAP) {
    extern __shared__ int hist[];   // NB ints
    const int tid = threadIdx.x;
    for (int i = tid; i < NB; i += SC_BLOCK) hist[i] = 0;
    __syncthreads();

    const int is64 = *flag;
    const long long base_e = (long long)blockIdx.x * (SC_BLOCK * SC_EPT);
    const long long* raw64 = (const long long*)raw;

    // rp[j]: (bkt<<19) | (drow<<14) | rank   (NB <= 2047, drow<32, rank<16384)
    int rp[SC_EPT];
#pragma unroll
    for (int j = 0; j < SC_EPT; ++j) {
        long long e = base_e + tid + (long long)j * SC_BLOCK;
        int v = -1;
        if (e < E) {
            int d = is64 ? (int)raw64[E + e] : raw[E + e];
            int bkt = d >> RB_SHIFT;
            int rank = atomicAdd(&hist[bkt], 1);
            v = (bkt << 19) | ((d & (RB - 1)) << 14) | rank;
        }
        rp[j] = v;
    }
    __syncthreads();

    // Reserve a contiguous range per touched bucket; hist[] becomes base.
    for (int i = tid; i < NB; i += SC_BLOCK) {
        int c = hist[i];
        hist[i] = (c > 0) ? atomicAdd(&cursor[i], c) : 0;
    }
    __syncthreads();

#pragma unroll
    for (int j = 0; j < SC_EPT; ++j) {
        if (rp[j] < 0) continue;
        long long e = base_e + tid + (long long)j * SC_BLOCK;
        int bkt  = rp[j] >> 19;
        int drow = (rp[j] >> 14) & (RB - 1);
        int rank = rp[j] & 16383;
        int s = is64 ? (int)raw64[e] : raw[e];
        float v = vals[e];
        int off = hist[bkt] + rank;
        if (off < CAP) {
            u64 rec = ((u64)__float_as_uint(v) << 32) | ((u64)(uint)s << 6) | (u64)drow;
            __builtin_nontemporal_store(rec, &packed[(size_t)bkt * CAP + off]);
        }
    }
}

// K3: one block per 32-row bucket. 512 threads = 16 slots x 32 batches.
// Phase 1: bulk-stage CHUNK records to LDS (coalesced, independent).
// Phase 2: decode 8 records from LDS -> 8 independent xt gathers -> ds_add.
#define RD_BLOCK 512
#define RD_K 8
#define RD_CHUNK 1024
__global__ __launch_bounds__(RD_BLOCK)
void SL_bucket_reduce_kernel(const u64* __restrict__ packed, const int* __restrict__ cursor,
                             const __hip_bfloat16* __restrict__ xt,
                             const float* __restrict__ bias,
                             float* __restrict__ out, int M, int CAP) {
    __shared__ float acc[RB][33];
    __shared__ u64 srec[RD_CHUNK];
    const int tid = threadIdx.x;
    for (int i = tid; i < RB * 33; i += RD_BLOCK) ((float*)acc)[i] = 0.0f;

    const int bkt  = blockIdx.x;
    const int row0 = bkt << RB_SHIFT;
    int nE = cursor[bkt];
    if (nE > CAP) nE = CAP;
    const u64* pb = packed + (size_t)bkt * CAP;

    const int slot = tid >> 5;           // 0..15
    const int b    = tid & 31;           // batch lane

    for (int c0 = 0; c0 < nE; c0 += RD_CHUNK) {
        int cn  = nE - c0; if (cn > RD_CHUNK) cn = RD_CHUNK;
        int cnp = (cn + 127) & ~127;     // pad to multiple of 16 slots * 8 deep
        __syncthreads();                  // LDS reuse guard (also covers acc init)
        for (int i = tid; i < cnp; i += RD_BLOCK) {
            u64 r = (i < cn) ? __builtin_nontemporal_load(&pb[c0 + i]) : 0ULL;
            srec[i] = r;                  // zero rec: s=0,v=0,row=0 -> adds 0
        }
        __syncthreads();

        for (int base = slot * RD_K; base < cnp; base += 16 * RD_K) {
            int s[RD_K]; int r[RD_K]; float v[RD_K];
#pragma unroll
            for (int j = 0; j < RD_K; ++j) {
                u64 p = srec[base + j];   // broadcast ds_read, cheap
                s[j] = (int)((p >> 6) & 0x3FFFFFFu);
                r[j] = (int)(p & (RB - 1));
                v[j] = __uint_as_float((uint32_t)(p >> 32));
            }
            float xv[RD_K];
#pragma unroll
            for (int j = 0; j < RD_K; ++j)
                xv[j] = __bfloat162float(xt[(size_t)s[j] * 32 + b]);  // 8 independent gathers
#pragma unroll
            for (int j = 0; j < RD_K; ++j)
                atomicAdd(&acc[r[j]][b], v[j] * xv[j]);
        }
    }
    __syncthreads();

    // Write out[b, row0+r] = acc[r][b] + bias[row0+r], coalesced over r.
    for (int i = tid; i < RB * 32; i += RD_BLOCK) {
        int rr = i & (RB - 1);
        int bb = i >> RB_SHIFT;
        int m  = row0 + rr;
        if (m < M)
            __builtin_nontemporal_store(acc[rr][bb] + bias[m], &out[(size_t)bb * M + m]);
    }
}

// ----------------- tier-2 fallback: direct atomic scatter ------------------

__global__ void SL_zero_kernel(int* __restrict__ p, long long n) {
    long long tid = (long long)blockIdx.x * blockDim.x + threadIdx.x;
    if (tid < n) p[tid] = 0;
}

__global__ void SL_convert_kernel(const int* __restrict__ raw, int* __restrict__ out,
                                  long long n, const int* __restrict__ flag) {
    long long tid = (long long)blockIdx.x * blockDim.x + threadIdx.x;
    if (tid >= n) return;
    const int is64 = *flag;
    out[tid] = is64 ? raw[tid * 2] : raw[tid];
}

__global__ void SL_prep_flat_kernel(const float* __restrict__ x, float* __restrict__ xt, int N) {
    long long tid = (long long)blockIdx.x * blockDim.x + threadIdx.x;
    long long totalN = (long long)N * 32;
    if (tid >= totalN) return;
    int n = (int)(tid >> 5);
    int b = (int)(tid & 31);
    xt[tid] = x[(long long)b * N + n];
}

__global__ void SL_scatter_kernel(const int* __restrict__ src, const int* __restrict__ dst,
                                  const float* __restrict__ vals, const float* __restrict__ xt,
                                  float* __restrict__ out_t, long long E) {
    long long tid = (long long)blockIdx.x * blockDim.x + threadIdx.x;
    long long e = tid >> 3;
    if (e >= E) return;
    int b0 = (int)(tid & 7) * 4;
    int s = src[e];
    int d = dst[e];
    float v = vals[e];
    const float4 xv = *reinterpret_cast<const float4*>(xt + (long long)s * 32 + b0);
    float* op = out_t + (long long)d * 32 + b0;
#if defined(__HIP_DEVICE_COMPILE__)
    unsafeAtomicAdd(op + 0, v * xv.x);
    unsafeAtomicAdd(op + 1, v * xv.y);
    unsafeAtomicAdd(op + 2, v * xv.z);
    unsafeAtomicAdd(op + 3, v * xv.w);
#endif
}

__global__ void SL_finalize_kernel(const float* __restrict__ out_t, const float* __restrict__ bias,
                                   float* __restrict__ out, int M) {
    __shared__ float tile[32][33];
    int m0 = blockIdx.x * 32;
    int tx = threadIdx.x;
    int ty = threadIdx.y;
    int m = m0 + ty;
    if (m < M) tile[ty][tx] = out_t[(long long)m * 32 + tx];
    __syncthreads();
    int mm = m0 + tx;
    if (mm < M) out[(long long)ty * M + mm] = tile[tx][ty] + bias[mm];
}

// ----------------- tier-3 fallback: fully generic ------------------

__global__ void SL_init_out_kernel(const float* __restrict__ bias, float* __restrict__ out,
                                   int M, long long total) {
    long long tid = (long long)blockIdx.x * blockDim.x + threadIdx.x;
    if (tid < total) out[tid] = bias[tid % M];
}

__global__ void SL_scatter_direct_kernel(const int* __restrict__ raw, const int* __restrict__ flag,
                                         const float* __restrict__ vals, const float* __restrict__ x,
                                         float* __restrict__ out, long long E, int N, int M, int B) {
    long long e = (long long)blockIdx.x * blockDim.x + threadIdx.x;
    if (e >= E) return;
    const int is64 = *flag;
    long long s = is64 ? raw[2 * e] : raw[e];
    long long d = is64 ? raw[2 * (E + e)] : raw[E + e];
    float v = vals[e];
    for (int b = 0; b < B; ++b) {
#if defined(__HIP_DEVICE_COMPILE__)
        unsafeAtomicAdd(&out[(long long)b * M + d], v * x[(long long)b * N + s]);
#endif
    }
}

extern "C" void kernel_launch(void* const* d_in, const int* in_sizes, int n_in,
                              void* d_out, int out_size, void* d_ws, size_t ws_size,
                              hipStream_t stream) {
    const float* x       = (const float*)d_in[0];
    const int*   idx_raw = (const int*)d_in[1];
    const float* vals    = (const float*)d_in[2];
    const float* bias    = (const float*)d_in[3];
    float*       out     = (float*)d_out;

    const long long twoE = in_sizes[1];
    const long long E    = twoE / 2;
    const int M = in_sizes[3];
    const int B = out_size / M;
    const int N = in_sizes[0] / B;

    // ---- tier 1: 32-row bucket path, bf16 xt ----
    const int NB = (M + RB - 1) >> RB_SHIFT;
    double mean = (double)E / (double)NB;
    int CAP = (int)(mean + 8.0 * sqrt(mean > 1.0 ? mean : 1.0) + 128.0);
    CAP = (CAP + 63) & ~63;

    const size_t xt_b = (((size_t)N * 32 * sizeof(__hip_bfloat16)) + 255) & ~(size_t)255;
    const size_t pk_b = (size_t)NB * (size_t)CAP * sizeof(u64);
    const size_t need1 = xt_b + pk_b + (size_t)NB * 4 + 64;

    // tier-2 needs
    const size_t need2 = ((size_t)(N + M) * 32 + (size_t)twoE + 1) * sizeof(int);

    if (B == 32 && N <= (1 << 26) && NB <= 2047 && ws_size >= need1) {
        char* ws = (char*)d_ws;
        __hip_bfloat16* xt = (__hip_bfloat16*)ws;
        u64*   packed = (u64*)(ws + xt_b);
        int*   cursor = (int*)(ws + xt_b + pk_b);
        int*   flag   = cursor + NB;

        SL_detect_zero_kernel<<<(NB + 255) / 256, 256, 0, stream>>>(
            (const uint32_t*)idx_raw, flag, cursor, NB);

        dim3 pblk(32, 32);
        SL_prep_kernel<<<(N + 31) / 32, pblk, 0, stream>>>(x, xt, N);

        long long epb = (long long)SC_BLOCK * SC_EPT;   // 8192 edges per block
        unsigned sgrid = (unsigned)((E + epb - 1) / epb);
        SL_bucket_scatter_kernel<<<sgrid, SC_BLOCK, NB * sizeof(int), stream>>>(
            idx_raw, flag, vals, packed, cursor, E, NB, CAP);

        SL_bucket_reduce_kernel<<<NB, RD_BLOCK, 0, stream>>>(
            packed, cursor, xt, bias, out, M, CAP);
    } else if (B == 32 && ws_size >= need2) {
        float* xtf   = (float*)d_ws;
        float* out_t = xtf + (size_t)N * 32;
        int*   idx32 = (int*)(out_t + (size_t)M * 32);
        int*   flag  = idx32 + twoE;

        SL_detect_zero_kernel<<<1, 256, 0, stream>>>((const uint32_t*)idx_raw, flag, flag, 0);
        SL_convert_kernel<<<(unsigned)((twoE + 255) / 256), 256, 0, stream>>>(
            idx_raw, idx32, twoE, flag);
        long long prep_total = (long long)N * 32;
        SL_prep_flat_kernel<<<(unsigned)((prep_total + 255) / 256), 256, 0, stream>>>(x, xtf, N);
        SL_zero_kernel<<<(unsigned)(((long long)M * 32 + 255) / 256), 256, 0, stream>>>(
            (int*)out_t, (long long)M * 32);
        long long sc_total = E * 8;
        SL_scatter_kernel<<<(unsigned)((sc_total + 255) / 256), 256, 0, stream>>>(
            idx32, idx32 + E, vals, xtf, out_t, E);
        dim3 blk(32, 32);
        SL_finalize_kernel<<<(M + 31) / 32, blk, 0, stream>>>(out_t, bias, out, M);
    } else if (ws_size >= sizeof(int)) {
        int* flag = (int*)d_ws;
        SL_detect_zero_kernel<<<1, 256, 0, stream>>>((const uint32_t*)idx_raw, flag, flag, 0);
        long long total = (long long)B * M;
        SL_init_out_kernel<<<(unsigned)((total + 255) / 256), 256, 0, stream>>>(bias, out, M, total);
        SL_scatter_direct_kernel<<<(unsigned)((E + 255) / 256), 256, 0, stream>>>(
            idx_raw, flag, vals, x, out, E, N, M, B);
    }
}

// Round 7
// 367.194 us; speedup vs baseline: 1.0895x; 1.0895x over previous
//
#include <hip/hip_runtime.h>
#include <hip/hip_bf16.h>
#include <cstdint>
#include <cmath>

typedef unsigned long long u64;

// ---------------------------------------------------------------------------
// SparseLinear: out[b, dst[e]] += values[e] * x[b, src[e]]; out += bias
// Round 7: split-K reduce. R3-R6 showed reduce time (~320us) invariant to
// occupancy/MLP/footprint -> test block-level scaling: each 32-row bucket's
// edge list is split across 8 blocks with private accumulators; a combine
// kernel sums the 8 partials (+bias, transposed store).
// Packed edge record: [63:32]=val bits, [31:6]=src, [4:0]=dst&31.
// ---------------------------------------------------------------------------

#define RB        32          // rows per bucket
#define RB_SHIFT  5
#define SPLIT     8           // split-K factor

// K0: detect int64 vs int32 indices; zero bucket cursors.
__global__ void SL_detect_zero_kernel(const uint32_t* __restrict__ raw, int* __restrict__ flag,
                                      int* __restrict__ cursor, int NB) {
    int gid = blockIdx.x * blockDim.x + threadIdx.x;
    if (gid == 0) {
        int is64 = 1;
        for (int i = 1; i < 64; i += 2) {
            if (raw[i] != 0u) { is64 = 0; break; }
        }
        *flag = is64;
    }
    for (int i = gid; i < NB; i += gridDim.x * blockDim.x) cursor[i] = 0;
}

// K1: transpose x (32, N) -> xt (N, 32) in bf16. LDS 32x33 tile.
__global__ void SL_prep_kernel(const float* __restrict__ x, __hip_bfloat16* __restrict__ xt,
                               int N) {
    __shared__ float tile[32][33];
    int n0 = blockIdx.x * 32;
    int tx = threadIdx.x, ty = threadIdx.y;
    int n = n0 + tx;
    if (n < N) tile[tx][ty] = x[(size_t)ty * N + n];
    __syncthreads();
    int n2 = n0 + ty;
    if (n2 < N) xt[(size_t)n2 * 32 + tx] = __float2bfloat16(tile[ty][tx]);
}

// K2: bucket scatter. Per-block LDS histogram + rank, one global atomic per
// (block,bucket) to reserve a contiguous slot range, packed 8B nt-writes.
#define SC_BLOCK 256
#define SC_EPT   32   // 8192 edges per block (rank fits 14 bits)
__global__ __launch_bounds__(SC_BLOCK)
void SL_bucket_scatter_kernel(const int* __restrict__ raw, const int* __restrict__ flag,
                              const float* __restrict__ vals, u64* __restrict__ packed,
                              int* __restrict__ cursor, long long E, int NB, int CAP) {
    extern __shared__ int hist[];   // NB ints
    const int tid = threadIdx.x;
    for (int i = tid; i < NB; i += SC_BLOCK) hist[i] = 0;
    __syncthreads();

    const int is64 = *flag;
    const long long base_e = (long long)blockIdx.x * (SC_BLOCK * SC_EPT);
    const long long* raw64 = (const long long*)raw;

    // rp[j]: (bkt<<19) | (drow<<14) | rank   (NB <= 2047, drow<32, rank<16384)
    int rp[SC_EPT];
#pragma unroll
    for (int j = 0; j < SC_EPT; ++j) {
        long long e = base_e + tid + (long long)j * SC_BLOCK;
        int v = -1;
        if (e < E) {
            int d = is64 ? (int)raw64[E + e] : raw[E + e];
            int bkt = d >> RB_SHIFT;
            int rank = atomicAdd(&hist[bkt], 1);
            v = (bkt << 19) | ((d & (RB - 1)) << 14) | rank;
        }
        rp[j] = v;
    }
    __syncthreads();

    // Reserve a contiguous range per touched bucket; hist[] becomes base.
    for (int i = tid; i < NB; i += SC_BLOCK) {
        int c = hist[i];
        hist[i] = (c > 0) ? atomicAdd(&cursor[i], c) : 0;
    }
    __syncthreads();

#pragma unroll
    for (int j = 0; j < SC_EPT; ++j) {
        if (rp[j] < 0) continue;
        long long e = base_e + tid + (long long)j * SC_BLOCK;
        int bkt  = rp[j] >> 19;
        int drow = (rp[j] >> 14) & (RB - 1);
        int rank = rp[j] & 16383;
        int s = is64 ? (int)raw64[e] : raw[e];
        float v = vals[e];
        int off = hist[bkt] + rank;
        if (off < CAP) {
            u64 rec = ((u64)__float_as_uint(v) << 32) | ((u64)(uint)s << 6) | (u64)drow;
            __builtin_nontemporal_store(rec, &packed[(size_t)bkt * CAP + off]);
        }
    }
}

// K3a: split-K reduce. grid = NB*SPLIT blocks of 256 (8 slots x 32 batches).
// Each block reduces its slice of one bucket into LDS, writes a 4KB partial.
#define RD_K 8
__global__ __launch_bounds__(256)
void SL_split_reduce_kernel(const u64* __restrict__ packed, const int* __restrict__ cursor,
                            const __hip_bfloat16* __restrict__ xt,
                            float* __restrict__ partial, int CAP) {
    __shared__ float acc[RB][33];
    const int tid = threadIdx.x;
    for (int i = tid; i < RB * 33; i += 256) ((float*)acc)[i] = 0.0f;
    __syncthreads();

    const int bx  = blockIdx.x;
    const int bkt = bx >> 3;          // / SPLIT
    const int sl  = bx & (SPLIT - 1);
    int nE = cursor[bkt];
    if (nE > CAP) nE = CAP;
    const int per   = (nE + SPLIT - 1) / SPLIT;
    const int start = sl * per;
    int end = start + per; if (end > nE) end = nE;
    const u64* pb = packed + (size_t)bkt * CAP;

    const int slot = tid >> 5;        // 0..7
    const int b    = tid & 31;        // batch lane

    for (int base = start + slot * RD_K; base < end; base += 8 * RD_K) {
        u64 p[RD_K];
#pragma unroll
        for (int j = 0; j < RD_K; ++j) {
            int k = base + j;
            p[j] = (k < end) ? __builtin_nontemporal_load(&pb[k]) : 0ULL;
        }
        float xv[RD_K];
#pragma unroll
        for (int j = 0; j < RD_K; ++j) {
            int s = (int)((p[j] >> 6) & 0x3FFFFFFu);
            xv[j] = __bfloat162float(xt[(size_t)s * 32 + b]);
        }
#pragma unroll
        for (int j = 0; j < RD_K; ++j) {
            float v = __uint_as_float((uint32_t)(p[j] >> 32));
            atomicAdd(&acc[(int)(p[j] & (RB - 1))][b], v * xv[j]);
        }
    }
    __syncthreads();

    float* pp = partial + ((size_t)bx << 10);       // 1024 floats per block
    for (int i = tid; i < RB * 32; i += 256)
        pp[i] = acc[i >> 5][i & 31];                // [r][b], coalesced
}

// K3b: combine SPLIT partials per bucket, add bias, transposed store to out.
__global__ __launch_bounds__(256)
void SL_combine_kernel(const float* __restrict__ partial, const float* __restrict__ bias,
                       float* __restrict__ out, int M) {
    __shared__ float acc[RB][33];
    const int bkt = blockIdx.x;
    const int tid = threadIdx.x;
    const float* pp = partial + ((size_t)(bkt * SPLIT) << 10);
    for (int i = tid; i < RB * 32; i += 256) {
        float s = 0.0f;
#pragma unroll
        for (int sl = 0; sl < SPLIT; ++sl) s += pp[(sl << 10) + i];
        acc[i >> 5][i & 31] = s;
    }
    __syncthreads();
    const int row0 = bkt << RB_SHIFT;
    for (int i = tid; i < RB * 32; i += 256) {
        int rr = i & (RB - 1);
        int bb = i >> RB_SHIFT;
        int m  = row0 + rr;
        if (m < M)
            __builtin_nontemporal_store(acc[rr][bb] + bias[m], &out[(size_t)bb * M + m]);
    }
}

// K3 (tier-1 fallback): one block per bucket, direct reduce (R5 structure).
__global__ __launch_bounds__(256)
void SL_bucket_reduce_kernel(const u64* __restrict__ packed, const int* __restrict__ cursor,
                             const __hip_bfloat16* __restrict__ xt,
                             const float* __restrict__ bias,
                             float* __restrict__ out, int M, int CAP) {
    __shared__ float acc[RB][33];
    const int tid = threadIdx.x;
    for (int i = tid; i < RB * 33; i += 256) ((float*)acc)[i] = 0.0f;
    __syncthreads();

    const int bkt  = blockIdx.x;
    const int row0 = bkt << RB_SHIFT;
    int nE = cursor[bkt];
    if (nE > CAP) nE = CAP;
    const u64* pb = packed + (size_t)bkt * CAP;

    const int slot = tid >> 5;
    const int b    = tid & 31;

    for (int base = slot * RD_K; base < nE; base += 8 * RD_K) {
        u64 p[RD_K];
#pragma unroll
        for (int j = 0; j < RD_K; ++j) {
            int k = base + j;
            p[j] = (k < nE) ? __builtin_nontemporal_load(&pb[k]) : 0ULL;
        }
        float xv[RD_K];
#pragma unroll
        for (int j = 0; j < RD_K; ++j) {
            int s = (int)((p[j] >> 6) & 0x3FFFFFFu);
            xv[j] = __bfloat162float(xt[(size_t)s * 32 + b]);
        }
#pragma unroll
        for (int j = 0; j < RD_K; ++j) {
            float v = __uint_as_float((uint32_t)(p[j] >> 32));
            atomicAdd(&acc[(int)(p[j] & (RB - 1))][b], v * xv[j]);
        }
    }
    __syncthreads();

    for (int i = tid; i < RB * 32; i += 256) {
        int rr = i & (RB - 1);
        int bb = i >> RB_SHIFT;
        int m  = row0 + rr;
        if (m < M)
            __builtin_nontemporal_store(acc[rr][bb] + bias[m], &out[(size_t)bb * M + m]);
    }
}

// ----------------- tier-2 fallback: direct atomic scatter ------------------

__global__ void SL_zero_kernel(int* __restrict__ p, long long n) {
    long long tid = (long long)blockIdx.x * blockDim.x + threadIdx.x;
    if (tid < n) p[tid] = 0;
}

__global__ void SL_convert_kernel(const int* __restrict__ raw, int* __restrict__ out,
                                  long long n, const int* __restrict__ flag) {
    long long tid = (long long)blockIdx.x * blockDim.x + threadIdx.x;
    if (tid >= n) return;
    const int is64 = *flag;
    out[tid] = is64 ? raw[tid * 2] : raw[tid];
}

__global__ void SL_prep_flat_kernel(const float* __restrict__ x, float* __restrict__ xt, int N) {
    long long tid = (long long)blockIdx.x * blockDim.x + threadIdx.x;
    long long totalN = (long long)N * 32;
    if (tid >= totalN) return;
    int n = (int)(tid >> 5);
    int b = (int)(tid & 31);
    xt[tid] = x[(long long)b * N + n];
}

__global__ void SL_scatter_kernel(const int* __restrict__ src, const int* __restrict__ dst,
                                  const float* __restrict__ vals, const float* __restrict__ xt,
                                  float* __restrict__ out_t, long long E) {
    long long tid = (long long)blockIdx.x * blockDim.x + threadIdx.x;
    long long e = tid >> 3;
    if (e >= E) return;
    int b0 = (int)(tid & 7) * 4;
    int s = src[e];
    int d = dst[e];
    float v = vals[e];
    const float4 xv = *reinterpret_cast<const float4*>(xt + (long long)s * 32 + b0);
    float* op = out_t + (long long)d * 32 + b0;
#if defined(__HIP_DEVICE_COMPILE__)
    unsafeAtomicAdd(op + 0, v * xv.x);
    unsafeAtomicAdd(op + 1, v * xv.y);
    unsafeAtomicAdd(op + 2, v * xv.z);
    unsafeAtomicAdd(op + 3, v * xv.w);
#endif
}

__global__ void SL_finalize_kernel(const float* __restrict__ out_t, const float* __restrict__ bias,
                                   float* __restrict__ out, int M) {
    __shared__ float tile[32][33];
    int m0 = blockIdx.x * 32;
    int tx = threadIdx.x;
    int ty = threadIdx.y;
    int m = m0 + ty;
    if (m < M) tile[ty][tx] = out_t[(long long)m * 32 + tx];
    __syncthreads();
    int mm = m0 + tx;
    if (mm < M) out[(long long)ty * M + mm] = tile[tx][ty] + bias[mm];
}

// ----------------- tier-3 fallback: fully generic ------------------

__global__ void SL_init_out_kernel(const float* __restrict__ bias, float* __restrict__ out,
                                   int M, long long total) {
    long long tid = (long long)blockIdx.x * blockDim.x + threadIdx.x;
    if (tid < total) out[tid] = bias[tid % M];
}

__global__ void SL_scatter_direct_kernel(const int* __restrict__ raw, const int* __restrict__ flag,
                                         const float* __restrict__ vals, const float* __restrict__ x,
                                         float* __restrict__ out, long long E, int N, int M, int B) {
    long long e = (long long)blockIdx.x * blockDim.x + threadIdx.x;
    if (e >= E) return;
    const int is64 = *flag;
    long long s = is64 ? raw[2 * e] : raw[e];
    long long d = is64 ? raw[2 * (E + e)] : raw[E + e];
    float v = vals[e];
    for (int b = 0; b < B; ++b) {
#if defined(__HIP_DEVICE_COMPILE__)
        unsafeAtomicAdd(&out[(long long)b * M + d], v * x[(long long)b * N + s]);
#endif
    }
}

extern "C" void kernel_launch(void* const* d_in, const int* in_sizes, int n_in,
                              void* d_out, int out_size, void* d_ws, size_t ws_size,
                              hipStream_t stream) {
    const float* x       = (const float*)d_in[0];
    const int*   idx_raw = (const int*)d_in[1];
    const float* vals    = (const float*)d_in[2];
    const float* bias    = (const float*)d_in[3];
    float*       out     = (float*)d_out;

    const long long twoE = in_sizes[1];
    const long long E    = twoE / 2;
    const int M = in_sizes[3];
    const int B = out_size / M;
    const int N = in_sizes[0] / B;

    const int NB = (M + RB - 1) >> RB_SHIFT;
    double mean = (double)E / (double)NB;
    int CAP = (int)(mean + 8.0 * sqrt(mean > 1.0 ? mean : 1.0) + 128.0);
    CAP = (CAP + 63) & ~63;

    const size_t xt_b   = (((size_t)N * 32 * sizeof(__hip_bfloat16)) + 255) & ~(size_t)255;
    const size_t pk_b   = (size_t)NB * (size_t)CAP * sizeof(u64);
    const size_t part_b = (size_t)NB * SPLIT * 1024 * sizeof(float);
    const size_t need0  = xt_b + pk_b + part_b + (size_t)NB * 4 + 64;   // split-K path
    const size_t need1  = xt_b + pk_b + (size_t)NB * 4 + 64;            // direct path
    const size_t need2  = ((size_t)(N + M) * 32 + (size_t)twoE + 1) * sizeof(int);

    if (B == 32 && N <= (1 << 26) && NB <= 2047 && ws_size >= need0) {
        char* ws = (char*)d_ws;
        __hip_bfloat16* xt = (__hip_bfloat16*)ws;
        u64*   packed  = (u64*)(ws + xt_b);
        float* partial = (float*)(ws + xt_b + pk_b);
        int*   cursor  = (int*)(ws + xt_b + pk_b + part_b);
        int*   flag    = cursor + NB;

        SL_detect_zero_kernel<<<(NB + 255) / 256, 256, 0, stream>>>(
            (const uint32_t*)idx_raw, flag, cursor, NB);

        dim3 pblk(32, 32);
        SL_prep_kernel<<<(N + 31) / 32, pblk, 0, stream>>>(x, xt, N);

        long long epb = (long long)SC_BLOCK * SC_EPT;
        unsigned sgrid = (unsigned)((E + epb - 1) / epb);
        SL_bucket_scatter_kernel<<<sgrid, SC_BLOCK, NB * sizeof(int), stream>>>(
            idx_raw, flag, vals, packed, cursor, E, NB, CAP);

        SL_split_reduce_kernel<<<NB * SPLIT, 256, 0, stream>>>(
            packed, cursor, xt, partial, CAP);

        SL_combine_kernel<<<NB, 256, 0, stream>>>(partial, bias, out, M);
    } else if (B == 32 && N <= (1 << 26) && NB <= 2047 && ws_size >= need1) {
        char* ws = (char*)d_ws;
        __hip_bfloat16* xt = (__hip_bfloat16*)ws;
        u64*   packed = (u64*)(ws + xt_b);
        int*   cursor = (int*)(ws + xt_b + pk_b);
        int*   flag   = cursor + NB;

        SL_detect_zero_kernel<<<(NB + 255) / 256, 256, 0, stream>>>(
            (const uint32_t*)idx_raw, flag, cursor, NB);
        dim3 pblk(32, 32);
        SL_prep_kernel<<<(N + 31) / 32, pblk, 0, stream>>>(x, xt, N);
        long long epb = (long long)SC_BLOCK * SC_EPT;
        unsigned sgrid = (unsigned)((E + epb - 1) / epb);
        SL_bucket_scatter_kernel<<<sgrid, SC_BLOCK, NB * sizeof(int), stream>>>(
            idx_raw, flag, vals, packed, cursor, E, NB, CAP);
        SL_bucket_reduce_kernel<<<NB, 256, 0, stream>>>(
            packed, cursor, xt, bias, out, M, CAP);
    } else if (B == 32 && ws_size >= need2) {
        float* xtf   = (float*)d_ws;
        float* out_t = xtf + (size_t)N * 32;
        int*   idx32 = (int*)(out_t + (size_t)M * 32);
        int*   flag  = idx32 + twoE;

        SL_detect_zero_kernel<<<1, 256, 0, stream>>>((const uint32_t*)idx_raw, flag, flag, 0);
        SL_convert_kernel<<<(unsigned)((twoE + 255) / 256), 256, 0, stream>>>(
            idx_raw, idx32, twoE, flag);
        long long prep_total = (long long)N * 32;
        SL_prep_flat_kernel<<<(unsigned)((prep_total + 255) / 256), 256, 0, stream>>>(x, xtf, N);
        SL_zero_kernel<<<(unsigned)(((long long)M * 32 + 255) / 256), 256, 0, stream>>>(
            (int*)out_t, (long long)M * 32);
        long long sc_total = E * 8;
        SL_scatter_kernel<<<(unsigned)((sc_total + 255) / 256), 256, 0, stream>>>(
            idx32, idx32 + E, vals, xtf, out_t, E);
        dim3 blk(32, 32);
        SL_finalize_kernel<<<(M + 31) / 32, blk, 0, stream>>>(out_t, bias, out, M);
    } else if (ws_size >= sizeof(int)) {
        int* flag = (int*)d_ws;
        SL_detect_zero_kernel<<<1, 256, 0, stream>>>((const uint32_t*)idx_raw, flag, flag, 0);
        long long total = (long long)B * M;
        SL_init_out_kernel<<<(unsigned)((total + 255) / 256), 256, 0, stream>>>(bias, out, M, total);
        SL_scatter_direct_kernel<<<(unsigned)((E + 255) / 256), 256, 0, stream>>>(
            idx_raw, flag, vals, x, out, E, N, M, B);
    }
}

// Round 8
// 364.731 us; speedup vs baseline: 1.0968x; 1.0068x over previous
//
#include <hip/hip_runtime.h>
#include <hip/hip_bf16.h>
#include <cstdint>
#include <cmath>

typedef unsigned long long u64;

// ---------------------------------------------------------------------------
// SparseLinear: out[b, dst[e]] += values[e] * x[b, src[e]]; out += bias
// Round 8: same split-K bucket pipeline as R7; the reduce's 8-deep xt gather
// is now forced into flight via inline asm (8x global_load_ushort, one
// s_waitcnt vmcnt(0), sched_barrier) -- R5-R7 VGPR counts (20/24/20) proved
// the compiler kept serializing the source-level batch (MLP=1 per wave).
// Packed edge record: [63:32]=val bits, [31:6]=src, [4:0]=dst&31.
// ---------------------------------------------------------------------------

#define RB        32          // rows per bucket
#define RB_SHIFT  5
#define SPLIT     8           // split-K factor

// K0: detect int64 vs int32 indices; zero bucket cursors.
__global__ void SL_detect_zero_kernel(const uint32_t* __restrict__ raw, int* __restrict__ flag,
                                      int* __restrict__ cursor, int NB) {
    int gid = blockIdx.x * blockDim.x + threadIdx.x;
    if (gid == 0) {
        int is64 = 1;
        for (int i = 1; i < 64; i += 2) {
            if (raw[i] != 0u) { is64 = 0; break; }
        }
        *flag = is64;
    }
    for (int i = gid; i < NB; i += gridDim.x * blockDim.x) cursor[i] = 0;
}

// K1: transpose x (32, N) -> xt (N, 32) in bf16. LDS 32x33 tile.
__global__ void SL_prep_kernel(const float* __restrict__ x, __hip_bfloat16* __restrict__ xt,
                               int N) {
    __shared__ float tile[32][33];
    int n0 = blockIdx.x * 32;
    int tx = threadIdx.x, ty = threadIdx.y;
    int n = n0 + tx;
    if (n < N) tile[tx][ty] = x[(size_t)ty * N + n];
    __syncthreads();
    int n2 = n0 + ty;
    if (n2 < N) xt[(size_t)n2 * 32 + tx] = __float2bfloat16(tile[ty][tx]);
}

// K2: bucket scatter. Per-block LDS histogram + rank, one global atomic per
// (block,bucket) to reserve a contiguous slot range, packed 8B nt-writes.
#define SC_BLOCK 256
#define SC_EPT   32   // 8192 edges per block (rank fits 14 bits)
__global__ __launch_bounds__(SC_BLOCK)
void SL_bucket_scatter_kernel(const int* __restrict__ raw, const int* __restrict__ flag,
                              const float* __restrict__ vals, u64* __restrict__ packed,
                              int* __restrict__ cursor, long long E, int NB, int CAP) {
    extern __shared__ int hist[];   // NB ints
    const int tid = threadIdx.x;
    for (int i = tid; i < NB; i += SC_BLOCK) hist[i] = 0;
    __syncthreads();

    const int is64 = *flag;
    const long long base_e = (long long)blockIdx.x * (SC_BLOCK * SC_EPT);
    const long long* raw64 = (const long long*)raw;

    // rp[j]: (bkt<<19) | (drow<<14) | rank   (NB <= 2047, drow<32, rank<16384)
    int rp[SC_EPT];
#pragma unroll
    for (int j = 0; j < SC_EPT; ++j) {
        long long e = base_e + tid + (long long)j * SC_BLOCK;
        int v = -1;
        if (e < E) {
            int d = is64 ? (int)raw64[E + e] : raw[E + e];
            int bkt = d >> RB_SHIFT;
            int rank = atomicAdd(&hist[bkt], 1);
            v = (bkt << 19) | ((d & (RB - 1)) << 14) | rank;
        }
        rp[j] = v;
    }
    __syncthreads();

    // Reserve a contiguous range per touched bucket; hist[] becomes base.
    for (int i = tid; i < NB; i += SC_BLOCK) {
        int c = hist[i];
        hist[i] = (c > 0) ? atomicAdd(&cursor[i], c) : 0;
    }
    __syncthreads();

#pragma unroll
    for (int j = 0; j < SC_EPT; ++j) {
        if (rp[j] < 0) continue;
        long long e = base_e + tid + (long long)j * SC_BLOCK;
        int bkt  = rp[j] >> 19;
        int drow = (rp[j] >> 14) & (RB - 1);
        int rank = rp[j] & 16383;
        int s = is64 ? (int)raw64[e] : raw[e];
        float v = vals[e];
        int off = hist[bkt] + rank;
        if (off < CAP) {
            u64 rec = ((u64)__float_as_uint(v) << 32) | ((u64)(uint)s << 6) | (u64)drow;
            __builtin_nontemporal_store(rec, &packed[(size_t)bkt * CAP + off]);
        }
    }
}

// K3a: split-K reduce. grid = NB*SPLIT blocks of 256 (8 slots x 32 batches).
// Each block reduces its slice of one bucket into LDS, writes a 4KB partial.
// Gather batch forced into flight via inline asm (8 outstanding loads).
#define RD_K 8
__global__ __launch_bounds__(256)
void SL_split_reduce_kernel(const u64* __restrict__ packed, const int* __restrict__ cursor,
                            const __hip_bfloat16* __restrict__ xt,
                            float* __restrict__ partial, int CAP) {
    __shared__ float acc[RB][33];
    const int tid = threadIdx.x;
    for (int i = tid; i < RB * 33; i += 256) ((float*)acc)[i] = 0.0f;
    __syncthreads();

    const int bx  = blockIdx.x;
    const int bkt = bx >> 3;          // / SPLIT
    const int sl  = bx & (SPLIT - 1);
    int nE = cursor[bkt];
    if (nE > CAP) nE = CAP;
    const int per   = (nE + SPLIT - 1) / SPLIT;
    const int start = sl * per;
    int end = start + per; if (end > nE) end = nE;
    const u64* pb = packed + (size_t)bkt * CAP;

    const int slot = tid >> 5;        // 0..7
    const int b    = tid & 31;        // batch lane

    for (int base = start + slot * RD_K; base < end; base += 8 * RD_K) {
        u64 p[RD_K];
#pragma unroll
        for (int j = 0; j < RD_K; ++j) {
            int k = base + j;
            p[j] = (k < end) ? pb[k] : 0ULL;   // zero rec: s=0,v=0,row=0 -> adds 0
        }
        // 8 forced-in-flight gathers (zero rec -> &xt[b], always in bounds).
        const __hip_bfloat16* a0 = xt + ((size_t)((p[0] >> 6) & 0x3FFFFFFu) * 32 + b);
        const __hip_bfloat16* a1 = xt + ((size_t)((p[1] >> 6) & 0x3FFFFFFu) * 32 + b);
        const __hip_bfloat16* a2 = xt + ((size_t)((p[2] >> 6) & 0x3FFFFFFu) * 32 + b);
        const __hip_bfloat16* a3 = xt + ((size_t)((p[3] >> 6) & 0x3FFFFFFu) * 32 + b);
        const __hip_bfloat16* a4 = xt + ((size_t)((p[4] >> 6) & 0x3FFFFFFu) * 32 + b);
        const __hip_bfloat16* a5 = xt + ((size_t)((p[5] >> 6) & 0x3FFFFFFu) * 32 + b);
        const __hip_bfloat16* a6 = xt + ((size_t)((p[6] >> 6) & 0x3FFFFFFu) * 32 + b);
        const __hip_bfloat16* a7 = xt + ((size_t)((p[7] >> 6) & 0x3FFFFFFu) * 32 + b);
        uint32_t r0, r1, r2, r3, r4, r5, r6, r7;
        asm volatile(
            "global_load_ushort %0, %8, off\n\t"
            "global_load_ushort %1, %9, off\n\t"
            "global_load_ushort %2, %10, off\n\t"
            "global_load_ushort %3, %11, off\n\t"
            "global_load_ushort %4, %12, off\n\t"
            "global_load_ushort %5, %13, off\n\t"
            "global_load_ushort %6, %14, off\n\t"
            "global_load_ushort %7, %15, off"
            : "=&v"(r0), "=&v"(r1), "=&v"(r2), "=&v"(r3),
              "=&v"(r4), "=&v"(r5), "=&v"(r6), "=&v"(r7)
            : "v"(a0), "v"(a1), "v"(a2), "v"(a3),
              "v"(a4), "v"(a5), "v"(a6), "v"(a7));
        asm volatile("s_waitcnt vmcnt(0)" ::: "memory");
        __builtin_amdgcn_sched_barrier(0);   // rule #18: keep uses after waitcnt

        uint32_t rr[RD_K] = {r0, r1, r2, r3, r4, r5, r6, r7};
#pragma unroll
        for (int j = 0; j < RD_K; ++j) {
            float xf = __uint_as_float(rr[j] << 16);           // bf16 -> f32
            float vv = __uint_as_float((uint32_t)(p[j] >> 32));
            atomicAdd(&acc[(int)(p[j] & (RB - 1))][b], vv * xf);
        }
    }
    __syncthreads();

    float* pp = partial + ((size_t)bx << 10);       // 1024 floats per block
    for (int i = tid; i < RB * 32; i += 256)
        pp[i] = acc[i >> 5][i & 31];                // [r][b], coalesced
}

// K3b: combine SPLIT partials per bucket, add bias, transposed store to out.
__global__ __launch_bounds__(256)
void SL_combine_kernel(const float* __restrict__ partial, const float* __restrict__ bias,
                       float* __restrict__ out, int M) {
    __shared__ float acc[RB][33];
    const int bkt = blockIdx.x;
    const int tid = threadIdx.x;
    const float* pp = partial + ((size_t)(bkt * SPLIT) << 10);
    for (int i = tid; i < RB * 32; i += 256) {
        float s = 0.0f;
#pragma unroll
        for (int sl = 0; sl < SPLIT; ++sl) s += pp[(sl << 10) + i];
        acc[i >> 5][i & 31] = s;
    }
    __syncthreads();
    const int row0 = bkt << RB_SHIFT;
    for (int i = tid; i < RB * 32; i += 256) {
        int rr = i & (RB - 1);
        int bb = i >> RB_SHIFT;
        int m  = row0 + rr;
        if (m < M)
            __builtin_nontemporal_store(acc[rr][bb] + bias[m], &out[(size_t)bb * M + m]);
    }
}

// K3 (tier-1 fallback): one block per bucket, direct reduce (R5 structure).
__global__ __launch_bounds__(256)
void SL_bucket_reduce_kernel(const u64* __restrict__ packed, const int* __restrict__ cursor,
                             const __hip_bfloat16* __restrict__ xt,
                             const float* __restrict__ bias,
                             float* __restrict__ out, int M, int CAP) {
    __shared__ float acc[RB][33];
    const int tid = threadIdx.x;
    for (int i = tid; i < RB * 33; i += 256) ((float*)acc)[i] = 0.0f;
    __syncthreads();

    const int bkt  = blockIdx.x;
    const int row0 = bkt << RB_SHIFT;
    int nE = cursor[bkt];
    if (nE > CAP) nE = CAP;
    const u64* pb = packed + (size_t)bkt * CAP;

    const int slot = tid >> 5;
    const int b    = tid & 31;

    for (int base = slot * RD_K; base < nE; base += 8 * RD_K) {
        u64 p[RD_K];
#pragma unroll
        for (int j = 0; j < RD_K; ++j) {
            int k = base + j;
            p[j] = (k < nE) ? pb[k] : 0ULL;
        }
        float xv[RD_K];
#pragma unroll
        for (int j = 0; j < RD_K; ++j) {
            int s = (int)((p[j] >> 6) & 0x3FFFFFFu);
            xv[j] = __bfloat162float(xt[(size_t)s * 32 + b]);
        }
#pragma unroll
        for (int j = 0; j < RD_K; ++j) {
            float v = __uint_as_float((uint32_t)(p[j] >> 32));
            atomicAdd(&acc[(int)(p[j] & (RB - 1))][b], v * xv[j]);
        }
    }
    __syncthreads();

    for (int i = tid; i < RB * 32; i += 256) {
        int rr = i & (RB - 1);
        int bb = i >> RB_SHIFT;
        int m  = row0 + rr;
        if (m < M)
            __builtin_nontemporal_store(acc[rr][bb] + bias[m], &out[(size_t)bb * M + m]);
    }
}

// ----------------- tier-2 fallback: direct atomic scatter ------------------

__global__ void SL_zero_kernel(int* __restrict__ p, long long n) {
    long long tid = (long long)blockIdx.x * blockDim.x + threadIdx.x;
    if (tid < n) p[tid] = 0;
}

__global__ void SL_convert_kernel(const int* __restrict__ raw, int* __restrict__ out,
                                  long long n, const int* __restrict__ flag) {
    long long tid = (long long)blockIdx.x * blockDim.x + threadIdx.x;
    if (tid >= n) return;
    const int is64 = *flag;
    out[tid] = is64 ? raw[tid * 2] : raw[tid];
}

__global__ void SL_prep_flat_kernel(const float* __restrict__ x, float* __restrict__ xt, int N) {
    long long tid = (long long)blockIdx.x * blockDim.x + threadIdx.x;
    long long totalN = (long long)N * 32;
    if (tid >= totalN) return;
    int n = (int)(tid >> 5);
    int b = (int)(tid & 31);
    xt[tid] = x[(long long)b * N + n];
}

__global__ void SL_scatter_kernel(const int* __restrict__ src, const int* __restrict__ dst,
                                  const float* __restrict__ vals, const float* __restrict__ xt,
                                  float* __restrict__ out_t, long long E) {
    long long tid = (long long)blockIdx.x * blockDim.x + threadIdx.x;
    long long e = tid >> 3;
    if (e >= E) return;
    int b0 = (int)(tid & 7) * 4;
    int s = src[e];
    int d = dst[e];
    float v = vals[e];
    const float4 xv = *reinterpret_cast<const float4*>(xt + (long long)s * 32 + b0);
    float* op = out_t + (long long)d * 32 + b0;
#if defined(__HIP_DEVICE_COMPILE__)
    unsafeAtomicAdd(op + 0, v * xv.x);
    unsafeAtomicAdd(op + 1, v * xv.y);
    unsafeAtomicAdd(op + 2, v * xv.z);
    unsafeAtomicAdd(op + 3, v * xv.w);
#endif
}

__global__ void SL_finalize_kernel(const float* __restrict__ out_t, const float* __restrict__ bias,
                                   float* __restrict__ out, int M) {
    __shared__ float tile[32][33];
    int m0 = blockIdx.x * 32;
    int tx = threadIdx.x;
    int ty = threadIdx.y;
    int m = m0 + ty;
    if (m < M) tile[ty][tx] = out_t[(long long)m * 32 + tx];
    __syncthreads();
    int mm = m0 + tx;
    if (mm < M) out[(long long)ty * M + mm] = tile[tx][ty] + bias[mm];
}

// ----------------- tier-3 fallback: fully generic ------------------

__global__ void SL_init_out_kernel(const float* __restrict__ bias, float* __restrict__ out,
                                   int M, long long total) {
    long long tid = (long long)blockIdx.x * blockDim.x + threadIdx.x;
    if (tid < total) out[tid] = bias[tid % M];
}

__global__ void SL_scatter_direct_kernel(const int* __restrict__ raw, const int* __restrict__ flag,
                                         const float* __restrict__ vals, const float* __restrict__ x,
                                         float* __restrict__ out, long long E, int N, int M, int B) {
    long long e = (long long)blockIdx.x * blockDim.x + threadIdx.x;
    if (e >= E) return;
    const int is64 = *flag;
    long long s = is64 ? raw[2 * e] : raw[e];
    long long d = is64 ? raw[2 * (E + e)] : raw[E + e];
    float v = vals[e];
    for (int b = 0; b < B; ++b) {
#if defined(__HIP_DEVICE_COMPILE__)
        unsafeAtomicAdd(&out[(long long)b * M + d], v * x[(long long)b * N + s]);
#endif
    }
}

extern "C" void kernel_launch(void* const* d_in, const int* in_sizes, int n_in,
                              void* d_out, int out_size, void* d_ws, size_t ws_size,
                              hipStream_t stream) {
    const float* x       = (const float*)d_in[0];
    const int*   idx_raw = (const int*)d_in[1];
    const float* vals    = (const float*)d_in[2];
    const float* bias    = (const float*)d_in[3];
    float*       out     = (float*)d_out;

    const long long twoE = in_sizes[1];
    const long long E    = twoE / 2;
    const int M = in_sizes[3];
    const int B = out_size / M;
    const int N = in_sizes[0] / B;

    const int NB = (M + RB - 1) >> RB_SHIFT;
    double mean = (double)E / (double)NB;
    int CAP = (int)(mean + 8.0 * sqrt(mean > 1.0 ? mean : 1.0) + 128.0);
    CAP = (CAP + 63) & ~63;

    const size_t xt_b   = (((size_t)N * 32 * sizeof(__hip_bfloat16)) + 255) & ~(size_t)255;
    const size_t pk_b   = (size_t)NB * (size_t)CAP * sizeof(u64);
    const size_t part_b = (size_t)NB * SPLIT * 1024 * sizeof(float);
    const size_t need0  = xt_b + pk_b + part_b + (size_t)NB * 4 + 64;   // split-K path
    const size_t need1  = xt_b + pk_b + (size_t)NB * 4 + 64;            // direct path
    const size_t need2  = ((size_t)(N + M) * 32 + (size_t)twoE + 1) * sizeof(int);

    if (B == 32 && N <= (1 << 26) && NB <= 2047 && ws_size >= need0) {
        char* ws = (char*)d_ws;
        __hip_bfloat16* xt = (__hip_bfloat16*)ws;
        u64*   packed  = (u64*)(ws + xt_b);
        float* partial = (float*)(ws + xt_b + pk_b);
        int*   cursor  = (int*)(ws + xt_b + pk_b + part_b);
        int*   flag    = cursor + NB;

        SL_detect_zero_kernel<<<(NB + 255) / 256, 256, 0, stream>>>(
            (const uint32_t*)idx_raw, flag, cursor, NB);

        dim3 pblk(32, 32);
        SL_prep_kernel<<<(N + 31) / 32, pblk, 0, stream>>>(x, xt, N);

        long long epb = (long long)SC_BLOCK * SC_EPT;
        unsigned sgrid = (unsigned)((E + epb - 1) / epb);
        SL_bucket_scatter_kernel<<<sgrid, SC_BLOCK, NB * sizeof(int), stream>>>(
            idx_raw, flag, vals, packed, cursor, E, NB, CAP);

        SL_split_reduce_kernel<<<NB * SPLIT, 256, 0, stream>>>(
            packed, cursor, xt, partial, CAP);

        SL_combine_kernel<<<NB, 256, 0, stream>>>(partial, bias, out, M);
    } else if (B == 32 && N <= (1 << 26) && NB <= 2047 && ws_size >= need1) {
        char* ws = (char*)d_ws;
        __hip_bfloat16* xt = (__hip_bfloat16*)ws;
        u64*   packed = (u64*)(ws + xt_b);
        int*   cursor = (int*)(ws + xt_b + pk_b);
        int*   flag   = cursor + NB;

        SL_detect_zero_kernel<<<(NB + 255) / 256, 256, 0, stream>>>(
            (const uint32_t*)idx_raw, flag, cursor, NB);
        dim3 pblk(32, 32);
        SL_prep_kernel<<<(N + 31) / 32, pblk, 0, stream>>>(x, xt, N);
        long long epb = (long long)SC_BLOCK * SC_EPT;
        unsigned sgrid = (unsigned)((E + epb - 1) / epb);
        SL_bucket_scatter_kernel<<<sgrid, SC_BLOCK, NB * sizeof(int), stream>>>(
            idx_raw, flag, vals, packed, cursor, E, NB, CAP);
        SL_bucket_reduce_kernel<<<NB, 256, 0, stream>>>(
            packed, cursor, xt, bias, out, M, CAP);
    } else if (B == 32 && ws_size >= need2) {
        float* xtf   = (float*)d_ws;
        float* out_t = xtf + (size_t)N * 32;
        int*   idx32 = (int*)(out_t + (size_t)M * 32);
        int*   flag  = idx32 + twoE;

        SL_detect_zero_kernel<<<1, 256, 0, stream>>>((const uint32_t*)idx_raw, flag, flag, 0);
        SL_convert_kernel<<<(unsigned)((twoE + 255) / 256), 256, 0, stream>>>(
            idx_raw, idx32, twoE, flag);
        long long prep_total = (long long)N * 32;
        SL_prep_flat_kernel<<<(unsigned)((prep_total + 255) / 256), 256, 0, stream>>>(x, xtf, N);
        SL_zero_kernel<<<(unsigned)(((long long)M * 32 + 255) / 256), 256, 0, stream>>>(
            (int*)out_t, (long long)M * 32);
        long long sc_total = E * 8;
        SL_scatter_kernel<<<(unsigned)((sc_total + 255) / 256), 256, 0, stream>>>(
            idx32, idx32 + E, vals, xtf, out_t, E);
        dim3 blk(32, 32);
        SL_finalize_kernel<<<(M + 31) / 32, blk, 0, stream>>>(out_t, bias, out, M);
    } else if (ws_size >= sizeof(int)) {
        int* flag = (int*)d_ws;
        SL_detect_zero_kernel<<<1, 256, 0, stream>>>((const uint32_t*)idx_raw, flag, flag, 0);
        long long total = (long long)B * M;
        SL_init_out_kernel<<<(unsigned)((total + 255) / 256), 256, 0, stream>>>(bias, out, M, total);
        SL_scatter_direct_kernel<<<(unsigned)((E + 255) / 256), 256, 0, stream>>>(
            idx_raw, flag, vals, x, out, E, N, M, B);
    }
}